// Round 9
// baseline (283.081 us; speedup 1.0000x reference)
//
#include <hip/hip_runtime.h>
#include <math.h>

#define BB    16
#define NN    64
#define EE    512
#define CIMG  512
#define H1D   256
#define H2D   128
#define H3D   64
#define UD    8
#define RD    8
#define BBCD  9
#define EH1D  64
#define EH2D  64
#define EPSF  1e-5f

typedef float nfloat4 __attribute__((ext_vector_type(4)));  // native vec for nontemporal builtins

// ---------------------------------------------------------------------------
// Restructure (R7): slab-owner design.
//   Kernel 1 (272 blocks): prep (see/cnt) + node MLP (node_c). Verbatim paths.
//   Kernel 2 (1024 blocks): block (b,i) OWNS output slab [64][64][8]:
//     - stages attr/we1/we2/wei once, computes P[j],Q[j] for the 64 candidate
//       nodes s_j (e1 row (j,k) = relu(P[s_j]+Q[s_k]) -- reassociated),
//     - NT-zeros the complement region (j>=c rows + k>=c tails) -- addresses
//       DISJOINT from corner writes, so no ordering barrier needed,
//     - runs only ceil(c^2/64) 64-pair tiles through e2/e3 (avg c~9 -> ~1.7
//       tiles vs 1.0 full-row GEMM before, but rel round-trip + corner kernel
//       + 2048 fill blocks are all eliminated),
//     - writes its out_node row from node_c.
//   Zero stores are issued AFTER all global reads (we2 staged in LDS), so no
//   subsequent vmcnt wait drains the 128 KiB/block store queue (R7 analysis).
// ---------------------------------------------------------------------------

// ======================= Kernel 1: prep + node MLP =========================
__global__ __launch_bounds__(256) void prepnode_kernel(
    const int* __restrict__ edge_index,
    int* __restrict__ see, int* __restrict__ cnt,
    const float* __restrict__ roi,
    const float* __restrict__ w1, const float* __restrict__ b1,
    const float* __restrict__ g1, const float* __restrict__ bt1,
    const float* __restrict__ m1, const float* __restrict__ v1,
    const float* __restrict__ w2, const float* __restrict__ b2,
    const float* __restrict__ g2, const float* __restrict__ bt2,
    const float* __restrict__ m2, const float* __restrict__ v2,
    const float* __restrict__ w3, const float* __restrict__ b3,
    const float* __restrict__ wn, const float* __restrict__ bnc,
    float* __restrict__ node_c)
{
    __shared__ union {
        struct {                       // prep path: 20.5 KB
            int src[EE];
            int dst[EE];
            int see[NN * NN];
        } p;
        struct {                       // node MLP path: 23.5 KB
            float part[4096];
            float h1[4][H1D];
            float h2[4][H2D];
            float h3[4][H3D];
        } n;
    } sm;

    const int t = threadIdx.x;

    // ======================== prep path ====================================
    if (blockIdx.x < BB) {
        const int b = blockIdx.x;
        const int* ei = edge_index + b * 2 * EE;
        for (int e = t; e < EE; e += 256) {
            sm.p.src[e] = ei[e];
            sm.p.dst[e] = ei[EE + e];
        }
        for (int x = t; x < NN * NN; x += 256)
            sm.p.see[x] = ((x & (NN - 1)) == 0) ? (x >> 6) : 0;
        __syncthreads();

        if (t < NN) {
            int pos = 0;
            #pragma unroll 8
            for (int e = 0; e < EE; ++e) {
                if (sm.p.dst[e] == t) {
                    ++pos;
                    if (pos < NN) sm.p.see[t * NN + pos] = sm.p.src[e];
                }
            }
            int c = pos + 1;
            cnt[b * NN + t] = (c < NN) ? c : NN;
        }
        __syncthreads();

        int4* dst4 = (int4*)(see + b * NN * NN);
        const int4* src4 = (const int4*)sm.p.see;
        for (int x = t; x < (NN * NN) / 4; x += 256) dst4[x] = src4[x];
        return;
    }

    // ======================== node MLP path ================================
    const int row0 = (blockIdx.x - BB) * 4;
    float* part = sm.n.part;

    // layer 1: 512 -> 256. og = t&63 (4 cols), kg = t>>6 (K/4 slice)
    {
        const int og = t & 63, kg = t >> 6;
        const float4* w1v = (const float4*)w1;
        const float4* roiv = (const float4*)(roi + (size_t)row0 * CIMG);
        float acc[4][4];
        #pragma unroll
        for (int r = 0; r < 4; ++r)
            #pragma unroll
            for (int c = 0; c < 4; ++c) acc[r][c] = 0.f;

        for (int cq = 0; cq < 32; ++cq) {
            const int c4 = kg * 32 + cq;
            float x[4][4], w[4][4];
            #pragma unroll
            for (int r = 0; r < 4; ++r) {
                float4 v = roiv[r * 128 + c4];
                x[r][0] = v.x; x[r][1] = v.y; x[r][2] = v.z; x[r][3] = v.w;
            }
            #pragma unroll
            for (int q = 0; q < 4; ++q) {
                float4 v = w1v[(size_t)(c4 * 4 + q) * 64 + og];
                w[q][0] = v.x; w[q][1] = v.y; w[q][2] = v.z; w[q][3] = v.w;
            }
            #pragma unroll
            for (int r = 0; r < 4; ++r)
                #pragma unroll
                for (int q = 0; q < 4; ++q)
                    #pragma unroll
                    for (int c = 0; c < 4; ++c)
                        acc[r][c] = fmaf(x[r][q], w[q][c], acc[r][c]);
        }
        #pragma unroll
        for (int r = 0; r < 4; ++r) {
            float4 v = {acc[r][0], acc[r][1], acc[r][2], acc[r][3]};
            *(float4*)(part + (kg * 4 + r) * 256 + og * 4) = v;
        }
    }
    __syncthreads();
    {
        const int o = t;
        const float bias = b1[o];
        const float scale = rsqrtf(v1[o] + EPSF) * g1[o];
        const float beta = bt1[o];
        const float mu = m1[o];
        #pragma unroll
        for (int r = 0; r < 4; ++r) {
            float s = part[(0 * 4 + r) * 256 + o] + part[(1 * 4 + r) * 256 + o]
                    + part[(2 * 4 + r) * 256 + o] + part[(3 * 4 + r) * 256 + o];
            sm.n.h1[r][o] = fmaxf(0.f, (s + bias - mu) * scale + beta);
        }
    }
    __syncthreads();

    // layer 2: 256 -> 128
    {
        const int og = t & 31, kg = t >> 5;
        const float4* w2v = (const float4*)w2;
        float acc[4][4];
        #pragma unroll
        for (int r = 0; r < 4; ++r)
            #pragma unroll
            for (int c = 0; c < 4; ++c) acc[r][c] = 0.f;

        #pragma unroll
        for (int cq = 0; cq < 8; ++cq) {
            const int c4 = kg * 8 + cq;
            float x[4][4], w[4][4];
            #pragma unroll
            for (int r = 0; r < 4; ++r) {
                float4 v = *(const float4*)&sm.n.h1[r][c4 * 4];
                x[r][0] = v.x; x[r][1] = v.y; x[r][2] = v.z; x[r][3] = v.w;
            }
            #pragma unroll
            for (int q = 0; q < 4; ++q) {
                float4 v = w2v[(size_t)(c4 * 4 + q) * 32 + og];
                w[q][0] = v.x; w[q][1] = v.y; w[q][2] = v.z; w[q][3] = v.w;
            }
            #pragma unroll
            for (int r = 0; r < 4; ++r)
                #pragma unroll
                for (int q = 0; q < 4; ++q)
                    #pragma unroll
                    for (int c = 0; c < 4; ++c)
                        acc[r][c] = fmaf(x[r][q], w[q][c], acc[r][c]);
        }
        #pragma unroll
        for (int r = 0; r < 4; ++r) {
            float4 v = {acc[r][0], acc[r][1], acc[r][2], acc[r][3]};
            *(float4*)(part + (kg * 4 + r) * 128 + og * 4) = v;
        }
    }
    __syncthreads();
    {
        const int o = t & 127;
        const int rp = t >> 7;
        const float bias = b2[o];
        const float scale = rsqrtf(v2[o] + EPSF) * g2[o];
        const float beta = bt2[o];
        const float mu = m2[o];
        #pragma unroll
        for (int rr = 0; rr < 2; ++rr) {
            const int r = rp + rr * 2;
            float s = 0.f;
            #pragma unroll
            for (int kg = 0; kg < 8; ++kg) s += part[(kg * 4 + r) * 128 + o];
            sm.n.h2[r][o] = fmaxf(0.f, (s + bias - mu) * scale + beta);
        }
    }
    __syncthreads();

    // layer 3: 128 -> 64
    {
        const int og = t & 15, kg = t >> 4;
        const float4* w3v = (const float4*)w3;
        float acc[4][4];
        #pragma unroll
        for (int r = 0; r < 4; ++r)
            #pragma unroll
            for (int c = 0; c < 4; ++c) acc[r][c] = 0.f;

        #pragma unroll
        for (int cq = 0; cq < 2; ++cq) {
            const int c4 = kg * 2 + cq;
            float x[4][4], w[4][4];
            #pragma unroll
            for (int r = 0; r < 4; ++r) {
                float4 v = *(const float4*)&sm.n.h2[r][c4 * 4];
                x[r][0] = v.x; x[r][1] = v.y; x[r][2] = v.z; x[r][3] = v.w;
            }
            #pragma unroll
            for (int q = 0; q < 4; ++q) {
                float4 v = w3v[(size_t)(c4 * 4 + q) * 16 + og];
                w[q][0] = v.x; w[q][1] = v.y; w[q][2] = v.z; w[q][3] = v.w;
            }
            #pragma unroll
            for (int r = 0; r < 4; ++r)
                #pragma unroll
                for (int q = 0; q < 4; ++q)
                    #pragma unroll
                    for (int c = 0; c < 4; ++c)
                        acc[r][c] = fmaf(x[r][q], w[q][c], acc[r][c]);
        }
        #pragma unroll
        for (int r = 0; r < 4; ++r) {
            float4 v = {acc[r][0], acc[r][1], acc[r][2], acc[r][3]};
            *(float4*)(part + (kg * 4 + r) * 64 + og * 4) = v;
        }
    }
    __syncthreads();
    {
        const int o = t & 63;
        const int r = t >> 6;
        float s = b3[o];
        #pragma unroll
        for (int kg = 0; kg < 16; ++kg) s += part[(kg * 4 + r) * 64 + o];
        sm.n.h3[r][o] = fmaxf(0.f, s);
    }
    __syncthreads();

    if (t < 32) {
        const int o = t & 7, r = t >> 3;
        float a = bnc[o];
        #pragma unroll 8
        for (int c = 0; c < H3D; ++c) a = fmaf(sm.n.h3[r][c], wn[c * UD + o], a);
        node_c[(size_t)(row0 + r) * UD + o] = 1.f / (1.f + expf(-a));
    }
}

// ======================= Kernel 2: slab owner ==============================
// LDS ~75 KB -> 2 blocks/CU. Per block: stage -> out_node row -> P/Q ->
// NT-zero complement -> ceil(c^2/64) tiles of {build e1, e2 GEMM, e3+write}.
__global__ __launch_bounds__(256) void edgeslab_kernel(
    const float* __restrict__ bboxes,
    const float* __restrict__ dirs,
    const float* __restrict__ prios,
    const float* __restrict__ we1, const float* __restrict__ be1,
    const float* __restrict__ we2, const float* __restrict__ be2,
    const float* __restrict__ wei, const float* __restrict__ bei,
    const int* __restrict__ see, const int* __restrict__ cnt,
    const float* __restrict__ node_c,
    float* __restrict__ out_node, float* __restrict__ out_edge)
{
    __shared__ float e1L[NN * 68];          // 17.4 KB: e1 then e2 (stride 68)
    __shared__ float PL[NN * NN];           // 16 KB: P[j][o], node sLi[j]
    __shared__ float QL[NN * NN];           // 16 KB
    __shared__ float qwL[NN * EH1D];        // 16 KB: we2
    __shared__ float attrL[NN][BBCD];       // 2.25 KB
    __shared__ float we1L[2 * BBCD * EH1D]; // 4.5 KB
    __shared__ float weiL[EH2D * RD];       // 2 KB
    __shared__ float be1L[EH1D];
    __shared__ float be2L[EH2D];
    __shared__ float beiL[RD];
    __shared__ int   sLi[NN];
    __shared__ int   jkL[64];

    const int t = threadIdx.x;
    const int bi = blockIdx.x;              // b*NN + i
    const int b = bi >> 6;
    const int c = cnt[bi];

    // ---- stage (all global READS happen before any NT store is issued) ----
    if (t < NN) sLi[t] = see[bi * NN + t];
    if (t < NN) {
        const float* bbp = bboxes + (b * NN + t) * 4;
        const float* ddp = dirs + (b * NN + t) * 4;
        attrL[t][0] = bbp[0] * (1.0f / 1024.0f);
        attrL[t][1] = bbp[1] * (1.0f / 1024.0f);
        attrL[t][2] = bbp[2] * (1.0f / 1024.0f);
        attrL[t][3] = bbp[3] * (1.0f / 1024.0f);
        attrL[t][4] = ddp[0];
        attrL[t][5] = ddp[1];
        attrL[t][6] = ddp[2];
        attrL[t][7] = ddp[3];
        attrL[t][8] = prios[b * NN + t];
    }
    for (int x = t; x < 2 * BBCD * EH1D; x += 256) we1L[x] = we1[x];
    {
        const float4* w4 = (const float4*)we2;
        float4* qw4 = (float4*)qwL;
        #pragma unroll
        for (int x = 0; x < 4; ++x) qw4[x * 256 + t] = w4[x * 256 + t];
    }
    if (t < 128) ((float4*)weiL)[t] = ((const float4*)wei)[t];
    if (t < EH1D) be1L[t] = be1[t];
    if (t < EH2D) be2L[t] = be2[t];
    if (t < RD)   beiL[t] = bei[t];
    __syncthreads();

    // ---- out_node row: out_node[bi][k] = node_c[b, s_k] * (k<c) -----------
    if (t < NN) {
        const float m = (t < c) ? 1.f : 0.f;
        const float4* src = (const float4*)(node_c + (size_t)(b * NN + sLi[t]) * UD);
        float4 v0 = src[0], v1 = src[1];
        v0.x *= m; v0.y *= m; v0.z *= m; v0.w *= m;
        v1.x *= m; v1.y *= m; v1.z *= m; v1.w *= m;
        float4* dst = (float4*)(out_node + ((size_t)bi * NN + t) * UD);
        dst[0] = v0;
        dst[1] = v1;
    }

    // ---- P/Q for all 64 candidate rows (node n = sLi[j]; j>=c harmless) ---
    {
        const int o = t & 63, jw = t >> 6;
        #pragma unroll
        for (int jg = 0; jg < 16; ++jg) {
            const int j = jg * 4 + jw;
            const int n = sLi[j];
            float p = be1L[o], q = 0.f;
            #pragma unroll
            for (int cc = 0; cc < BBCD; ++cc) {
                p = fmaf(attrL[n][cc], we1L[cc * EH1D + o], p);
                q = fmaf(attrL[n][cc], we1L[(BBCD + cc) * EH1D + o], q);
            }
            PL[j * NN + o] = p;
            QL[j * NN + o] = q;
        }
    }

    // ---- NT-zero the complement (disjoint from corner writes) ------------
    float* slab = out_edge + (size_t)bi * (NN * NN * RD);
    {
        const nfloat4 z = {0.f, 0.f, 0.f, 0.f};
        // full rows j >= c: (64-c) rows x 128 float4
        const int nrow4 = (NN - c) * 128;
        for (int x = t; x < nrow4; x += 256) {
            const int row = c + (x >> 7);
            __builtin_nontemporal_store(
                z, (nfloat4*)(slab + (size_t)row * 512 + (size_t)(x & 127) * 4));
        }
        // tails j < c, k >= c: c*(64-c) elements x 2 float4
        const int w = NN - c;
        const int ntail = c * w * 2;
        for (int x = t; x < ntail; x += 256) {
            const int e = x >> 1, h = x & 1;
            const int j = e / w;                 // w>0 whenever loop runs
            const int k = c + (e - j * w);
            __builtin_nontemporal_store(
                z, (nfloat4*)(slab + (size_t)(j * NN + k) * RD + h * 4));
        }
    }
    __syncthreads();   // PL/QL visible; tiles below are pure-LDS + stores

    // ---- pair tiles --------------------------------------------------------
    const int npairs = c * c;
    const int ntiles = (npairs + 63) >> 6;
    for (int tt = 0; tt < ntiles; ++tt) {
        const int base = tt << 6;
        if (t < 64) {
            const int p = base + t;
            int u = 0xFFFF;
            if (p < npairs) { const int j = p / c; u = (j << 8) | (p - j * c); }
            jkL[t] = u;
        }
        __syncthreads();

        // build e1 rows: e1[row][o] = relu(P[j] + Q[k])
        {
            const int o = t & 63, pw = t >> 6;
            #pragma unroll
            for (int pg = 0; pg < 16; ++pg) {
                const int row = pg * 4 + pw;
                const int u = jkL[row];
                const int jj = (u >> 8) & 63, kk = u & 63;
                e1L[row * 68 + o] = fmaxf(0.f, PL[jj * NN + o] + QL[kk * NN + o]);
            }
        }
        __syncthreads();

        // e2 GEMM (4x4 blocking, rows ty+16r private per wave, in-place)
        {
            const int tx = t & 15, ty = t >> 4;
            const int o0 = tx * 4;
            float acc[4][4];
            #pragma unroll
            for (int r = 0; r < 4; ++r)
                #pragma unroll
                for (int o = 0; o < 4; ++o) acc[r][o] = 0.f;

            #pragma unroll 4
            for (int cg = 0; cg < 16; ++cg) {
                float ev[4][4];
                #pragma unroll
                for (int r = 0; r < 4; ++r) {
                    float4 v = *(const float4*)(e1L + (ty + 16 * r) * 68 + cg * 4);
                    ev[r][0] = v.x; ev[r][1] = v.y; ev[r][2] = v.z; ev[r][3] = v.w;
                }
                #pragma unroll
                for (int q = 0; q < 4; ++q) {
                    float4 wv = *(const float4*)(qwL + (cg * 4 + q) * EH1D + o0);
                    #pragma unroll
                    for (int r = 0; r < 4; ++r) {
                        acc[r][0] = fmaf(ev[r][q], wv.x, acc[r][0]);
                        acc[r][1] = fmaf(ev[r][q], wv.y, acc[r][1]);
                        acc[r][2] = fmaf(ev[r][q], wv.z, acc[r][2]);
                        acc[r][3] = fmaf(ev[r][q], wv.w, acc[r][3]);
                    }
                }
            }
            float4 bv = *(const float4*)(be2L + o0);
            #pragma unroll
            for (int r = 0; r < 4; ++r) {
                float4 v;
                v.x = fmaxf(0.f, acc[r][0] + bv.x);
                v.y = fmaxf(0.f, acc[r][1] + bv.y);
                v.z = fmaxf(0.f, acc[r][2] + bv.z);
                v.w = fmaxf(0.f, acc[r][3] + bv.w);
                *(float4*)(e1L + (ty + 16 * r) * 68 + o0) = v;
            }
        }
        __syncthreads();

        // e3 + sigmoid + corner write
        {
            const int row = t >> 2;
            const int r0 = (t & 3) * 2;
            const int u = jkL[row];
            float a0 = beiL[r0], a1 = beiL[r0 + 1];
            const float* e2row = e1L + row * 68;
            #pragma unroll
            for (int og = 0; og < 16; ++og) {
                float4 e2v = *(const float4*)(e2row + og * 4);
                float2 w0 = *(const float2*)(weiL + (og * 4 + 0) * RD + r0);
                float2 w1 = *(const float2*)(weiL + (og * 4 + 1) * RD + r0);
                float2 w2 = *(const float2*)(weiL + (og * 4 + 2) * RD + r0);
                float2 w3 = *(const float2*)(weiL + (og * 4 + 3) * RD + r0);
                a0 = fmaf(e2v.x, w0.x, a0); a1 = fmaf(e2v.x, w0.y, a1);
                a0 = fmaf(e2v.y, w1.x, a0); a1 = fmaf(e2v.y, w1.y, a1);
                a0 = fmaf(e2v.z, w2.x, a0); a1 = fmaf(e2v.z, w2.y, a1);
                a0 = fmaf(e2v.w, w3.x, a0); a1 = fmaf(e2v.w, w3.y, a1);
            }
            if (u != 0xFFFF) {
                const int j = u >> 8, k = u & 255;
                float2 o2;
                o2.x = 1.f / (1.f + expf(-a0));
                o2.y = 1.f / (1.f + expf(-a1));
                *(float2*)(slab + (size_t)(j * NN + k) * RD + r0) = o2;
            }
        }
        __syncthreads();   // e1L/jkL reused next tile
    }
}

// ---------------------------------------------------------------------------
extern "C" void kernel_launch(void* const* d_in, const int* in_sizes, int n_in,
                              void* d_out, int out_size, void* d_ws, size_t ws_size,
                              hipStream_t stream)
{
    const float* roi  = (const float*)d_in[0];
    const float* bbox = (const float*)d_in[1];
    const float* dirs = (const float*)d_in[2];
    const float* prio = (const float*)d_in[3];
    const float* w1   = (const float*)d_in[4];
    const float* b1   = (const float*)d_in[5];
    const float* g1   = (const float*)d_in[6];
    const float* bt1  = (const float*)d_in[7];
    const float* m1   = (const float*)d_in[8];
    const float* v1   = (const float*)d_in[9];
    const float* w2   = (const float*)d_in[10];
    const float* b2   = (const float*)d_in[11];
    const float* g2   = (const float*)d_in[12];
    const float* bt2  = (const float*)d_in[13];
    const float* m2   = (const float*)d_in[14];
    const float* v2   = (const float*)d_in[15];
    const float* w3   = (const float*)d_in[16];
    const float* b3   = (const float*)d_in[17];
    const float* wn   = (const float*)d_in[18];
    const float* bnc  = (const float*)d_in[19];
    const float* we1  = (const float*)d_in[20];
    const float* be1  = (const float*)d_in[21];
    const float* we2  = (const float*)d_in[22];
    const float* be2  = (const float*)d_in[23];
    const float* wei  = (const float*)d_in[24];
    const float* bei  = (const float*)d_in[25];
    const int* edge_index = (const int*)d_in[26];

    char* ws = (char*)d_ws;
    int*   see    = (int*)ws;   ws += (size_t)BB * NN * NN * 4;
    int*   cnt    = (int*)ws;   ws += (size_t)BB * NN * 4;
    float* node_c = (float*)ws; ws += (size_t)BB * NN * UD * 4;

    float* out_node = (float*)d_out;
    float* out_edge = (float*)d_out + (size_t)BB * NN * NN * UD;

    hipLaunchKernelGGL(prepnode_kernel,
                       dim3(BB + 256), dim3(256), 0, stream,
                       edge_index, see, cnt,
                       roi, w1, b1, g1, bt1, m1, v1,
                       w2, b2, g2, bt2, m2, v2,
                       w3, b3, wn, bnc, node_c);
    hipLaunchKernelGGL(edgeslab_kernel, dim3(BB * NN), dim3(256), 0, stream,
                       bbox, dirs, prio, we1, be1, we2, be2, wei, bei,
                       see, cnt, node_c, out_node, out_edge);
}